// Round 12
// baseline (2982.180 us; speedup 1.0000x reference)
//
#include <hip/hip_runtime.h>

// Problem constants
constexpr int B = 64, T = 1024, D = 128, H = 256;
// RNN partition: 32 groups (2 batches each) x 4 blocks of 1024 threads.
// 64 units/block x 16 k-lanes; fp16 weights LDS-stationary (147 KB), fp16
// dot2 math, fp32 carry path. Aggregate poll budget = 128 x 384 = 49K (= R4).
constexpr int NG = 32;   // groups
constexpr int GB = 2;    // batches per group
constexpr int GK = 4;    // blocks per group
constexpr int UO = 64;   // hidden units owned per block
constexpr int HCS = 24;  // hdec chunk stride in halves (16 data + 8 skew, 48B)

typedef _Float16 h2 __attribute__((ext_vector_type(2)));
typedef _Float16 h8 __attribute__((ext_vector_type(8)));

__device__ __forceinline__ float dot2f(h2 a, h2 b, float c) {
#if defined(__has_builtin) && __has_builtin(__builtin_amdgcn_fdot2)
    return __builtin_amdgcn_fdot2(a, b, c, false);
#else
    c = fmaf((float)a[0], (float)b[0], c);
    return fmaf((float)a[1], (float)b[1], c);
#endif
}
// acc += dot(8 fp16 in w, 8 fp16 in v)
#define DOT8(acc, w, v) do { \
    acc = dot2f(__builtin_shufflevector(w, w, 0, 1), __builtin_shufflevector(v, v, 0, 1), acc); \
    acc = dot2f(__builtin_shufflevector(w, w, 2, 3), __builtin_shufflevector(v, v, 2, 3), acc); \
    acc = dot2f(__builtin_shufflevector(w, w, 4, 5), __builtin_shufflevector(v, v, 4, 5), acc); \
    acc = dot2f(__builtin_shufflevector(w, w, 6, 7), __builtin_shufflevector(v, v, 6, 7), acc); } while (0)

__device__ __forceinline__ h8 packh8(float4 f0, float4 f1) {
    h8 v;
    v[0] = (_Float16)f0.x; v[1] = (_Float16)f0.y; v[2] = (_Float16)f0.z; v[3] = (_Float16)f0.w;
    v[4] = (_Float16)f1.x; v[5] = (_Float16)f1.y; v[6] = (_Float16)f1.z; v[7] = (_Float16)f1.w;
    return v;
}
__device__ __forceinline__ float sigmoidf_(float v) {
    return 1.f / (1.f + __expf(-v));
}
__device__ __forceinline__ float tanhf_(float v) {
    float e2 = __expf(2.f * v);
    return 1.f - 2.f / (e2 + 1.f);
}

// ---------------- P1: per-(b,d) scan over t (prefetch-unrolled) ----------------
__global__ __launch_bounds__(64) void prep_scan(
    const float* __restrict__ x, const int* __restrict__ mask,
    const float* __restrict__ ts, const float* __restrict__ it0,
    float* __restrict__ ffill, float* __restrict__ idelta,
    float* __restrict__ mean, float* __restrict__ tdlv)
{
    const int b = blockIdx.x;
    const int d = blockIdx.y * 64 + threadIdx.x;
    float prev_x = 0.f, prev_td = 0.f, osum = 0.f, mcnt = 0.f;
    float prev_ts = it0[b];               // init_time is (1,B) -> flat[b]
    const int baseT = b * T;
    constexpr int U = 16;
    for (int t0 = 0; t0 < T; t0 += U) {
        float xv[U]; int mv[U]; float tsv[U];
        #pragma unroll
        for (int uu = 0; uu < U; ++uu) {
            const int idx = (baseT + t0 + uu) * D + d;
            xv[uu] = x[idx];
            mv[uu] = mask[idx];
        }
        #pragma unroll
        for (int uu = 0; uu < U; ++uu) tsv[uu] = ts[baseT + t0 + uu];
        #pragma unroll
        for (int uu = 0; uu < U; ++uu) {
            const float td = tsv[uu] - prev_ts;
            prev_ts = tsv[uu];
            const int idx = (baseT + t0 + uu) * D + d;
            if (!mv[uu]) { prev_x = xv[uu]; osum += xv[uu]; } else { mcnt += 1.f; }
            prev_td += td;
            ffill[idx]  = prev_x;
            idelta[idx] = prev_td;
            if (!mv[uu]) prev_td = 0.f;
            if (d == 0) tdlv[baseT + t0 + uu] = logf(fminf(fmaxf(td, 0.f), 1000.f));
        }
    }
    mean[b * D + d] = osum / fmaxf(mcnt, 1.f);
}

// ---------------- P2: imputation matvec (emits fp16 x) ----------------
constexpr int ROWS = 64;   // (b,t) rows per block
__global__ __launch_bounds__(256) void fill_kernel(
    const float* __restrict__ x, const int* __restrict__ mask,
    const float* __restrict__ ffill, const float* __restrict__ idelta,
    const float* __restrict__ mean, const float* __restrict__ idw,
    const float* __restrict__ idb, _Float16* __restrict__ xh)
{
    __shared__ float widw[128 * 129];   // padded: conflict-free
    __shared__ float ide[2][128];
    const int tid = threadIdx.x;
    for (int i = tid; i < 128 * 128; i += 256)
        widw[(i >> 7) * 129 + (i & 127)] = idw[i];
    __syncthreads();
    const int p = tid >> 7, d = tid & 127;
    const float bias = idb[d];
    const int row0 = blockIdx.x * ROWS;
    for (int r = 0; r < ROWS; r += 2) {
        const int rowp = row0 + r + p;    // b*T + t
        const int idx = rowp * D + d;
        ide[p][d] = fminf(fmaxf(idelta[idx] - 1.f, 0.f), 1000.f);
        __syncthreads();
        float acc = bias;
        #pragma unroll
        for (int k = 0; k < 128; ++k)
            acc = fmaf(ide[p][k], widw[d * 129 + k], acc);
        float fw = __expf(-fmaxf(acc, 0.f));
        float filled = ffill[idx] * fw + (1.f - fw) * mean[(rowp >> 10) * D + d];
        xh[idx] = (_Float16)(mask[idx] ? filled : x[idx]);
        __syncthreads();
    }
}

// ---------------- P3: persistent grouped GRU-D recurrence ----------------
// 32 two-batch groups x 4 blocks x 1024 thr (64 units x 16 lanes). Weights
// fp16 in LDS (one-time pack); gate math via v_dot2_f32_f16; fp32 carry via
// hown. Fence-free tagged 64-bit LLC exchange, parity double-buffered fp16
// hdec (stride-24-half chunks), one barrier/step, publisher pre-staging.
__global__ __launch_bounds__(1024, 4) void rnn_kernel(
    const _Float16* __restrict__ xh, const float* __restrict__ tdlv,
    const float* __restrict__ w_ih, const float* __restrict__ w_hh,
    const float* __restrict__ b_ih, const float* __restrict__ b_hh,
    const float* __restrict__ hdw, const float* __restrict__ hdb,
    unsigned long long* __restrict__ hx, float* __restrict__ out)
{
    const int tid = threadIdx.x;
    const int g  = blockIdx.x & (NG - 1);   // group; members bid%32==g -> same XCD
    const int kb = blockIdx.x >> 5;         // 0..3: owns units [kb*64, kb*64+64)
    const int u  = tid >> 4;                // 0..63 unit-local
    const int kc = tid & 15;                // 0..15 k-lane
    const int row = kb * UO + u;            // owned hidden unit
    const int b0 = g * GB;

    // LDS: fp16 weights, thread-chunk-sequential h8 layout.
    // gh chunks c = gate*2 + jc (0..5): k in [kc*16 + jc*8, +8)
    // gi chunks c = 6 + gate (6..8):    k in [kc*8, +8)
    __shared__ _Float16 wlds[9 * 1024 * 8];      // 147456 B
    __shared__ _Float16 hdech[2][GB][16 * HCS];  // 3072 B
    __shared__ float    hown[2][GB][UO];         // 1024 B   (total 151552 B)

    #pragma unroll
    for (int gg = 0; gg < 3; ++gg) {
        #pragma unroll
        for (int jc = 0; jc < 2; ++jc) {
            const float* wh = w_hh + (size_t)(row + gg * H) * H + kc * 16 + jc * 8;
            *(h8*)&wlds[((gg * 2 + jc) * 1024 + tid) * 8] =
                packh8(*(const float4*)wh, *(const float4*)(wh + 4));
        }
        const float* wi = w_ih + (size_t)(row + gg * H) * D + kc * 8;
        *(h8*)&wlds[((6 + gg) * 1024 + tid) * 8] =
            packh8(*(const float4*)wi, *(const float4*)(wi + 4));
    }
    for (int i = tid; i < 2 * GB * 16 * HCS; i += 1024)
        ((_Float16*)hdech)[i] = (_Float16)0.f;   // h0 = 0
    for (int i = tid; i < 2 * GB * UO; i += 1024)
        ((float*)hown)[i] = 0.f;

    // Staging role: threads 0..511 -> (batch sbb = tid>>8 in {0,1}, unit sk)
    const int sk = tid & 255;
    const int sbb = (tid >> 8) & 1;
    const bool stager = (tid < 512);
    const bool ownk = stager && ((sk >> 6) == kb);
    const float hdwk = hdw[sk], hdbk = hdb[sk];
    const float hdwo = hdw[row], hdbo = hdb[row];
    const bool pub = ((kc & 7) == 0);       // publisher lanes kc in {0,8}
    const int pbb = kc >> 3;                // published batch (0/1)
    const float br  = b_ih[row] + b_hh[row];
    const float bz  = b_ih[H + row] + b_hh[H + row];
    const float bnx = b_ih[2 * H + row];
    const float bnh = b_hh[2 * H + row];
    __syncthreads();

    for (int t = 0; t < T; ++t) {
        const int par = t & 1;

        // ---- (a) probe the remote tag word early (hide under gi) ----
        const bool need = (t > 0) && stager && !ownk;
        const unsigned long long* slot =
            hx + (size_t)((t - 1) & 1) * (B * H) + (size_t)(b0 + sbb) * H + sk;
        unsigned long long v = 0;
        if (need)
            v = __hip_atomic_load(slot, __ATOMIC_RELAXED, __HIP_MEMORY_SCOPE_AGENT);

        // ---- (b) gi partials: fp16 LDS weights x fp16 x via dot2 ----
        float acc[8];   // acc[bb*4 + gate]; gate 0=r 1=z 2=nx 3=nh
        #pragma unroll
        for (int i = 0; i < 8; ++i) acc[i] = 0.f;
        h8 wgi0 = *(const h8*)&wlds[((6 + 0) * 1024 + tid) * 8];
        h8 wgi1 = *(const h8*)&wlds[((6 + 1) * 1024 + tid) * 8];
        h8 wgi2 = *(const h8*)&wlds[((6 + 2) * 1024 + tid) * 8];
        #pragma unroll
        for (int bb = 0; bb < GB; ++bb) {
            h8 xv = *(const h8*)&xh[(size_t)((b0 + bb) * T + t) * D + kc * 8];
            DOT8(acc[bb * 4 + 0], wgi0, xv);
            DOT8(acc[bb * 4 + 1], wgi1, xv);
            DOT8(acc[bb * 4 + 2], wgi2, xv);
        }
        float tdn = 0.f;
        if (pub && t + 1 < T) tdn = tdlv[(b0 + pbb) * T + t + 1];

        // ---- (c) finish poll + stage decayed remote h (fp16) into LDS ----
        if (need) {
            while ((unsigned)(v >> 32) != (unsigned)t)
                v = __hip_atomic_load(slot, __ATOMIC_RELAXED, __HIP_MEMORY_SCOPE_AGENT);
            float hv = __uint_as_float((unsigned)v);
            float dec = __expf(-fmaxf(tdlv[(b0 + sbb) * T + t] * hdwk + hdbk, 0.f));
            hdech[par][sbb][(sk >> 4) * HCS + (sk & 15)] = (_Float16)(hv * dec);
        }
        __syncthreads();

        // ---- (d) gh partials: fp16 LDS weights x fp16 hdec via dot2 ----
        h8 wh00 = *(const h8*)&wlds[((0) * 1024 + tid) * 8];
        h8 wh01 = *(const h8*)&wlds[((1) * 1024 + tid) * 8];
        h8 wh10 = *(const h8*)&wlds[((2) * 1024 + tid) * 8];
        h8 wh11 = *(const h8*)&wlds[((3) * 1024 + tid) * 8];
        h8 wh20 = *(const h8*)&wlds[((4) * 1024 + tid) * 8];
        h8 wh21 = *(const h8*)&wlds[((5) * 1024 + tid) * 8];
        #pragma unroll
        for (int bb = 0; bb < GB; ++bb) {
            const _Float16* hb = &hdech[par][bb][kc * HCS];
            h8 h0 = *(const h8*)hb;
            h8 h1 = *(const h8*)(hb + 8);
            DOT8(acc[bb * 4 + 0], wh00, h0); DOT8(acc[bb * 4 + 0], wh01, h1);
            DOT8(acc[bb * 4 + 1], wh10, h0); DOT8(acc[bb * 4 + 1], wh11, h1);
            DOT8(acc[bb * 4 + 3], wh20, h0); DOT8(acc[bb * 4 + 3], wh21, h1);
        }

        // ---- (e) reduce-scatter over 16 lanes (8 items); item(kc) = kc>>1 ----
        #pragma unroll
        for (int m = 8; m >= 2; m >>= 1) {
            const bool sel = (kc & m);
            #pragma unroll
            for (int j = 0; j < m / 2; ++j) {
                float lo = acc[j], hi = acc[j + m / 2];
                float keep = sel ? hi : lo;
                float send = sel ? lo : hi;
                acc[j] = keep + __shfl_xor(send, m, 64);
            }
        }
        float vfin = acc[0] + __shfl_xor(acc[0], 1, 64);   // full 16-lane sum
        float zv  = __shfl_xor(vfin, 2, 64);               // item +1 (z)
        float nxv = __shfl_xor(vfin, 4, 64);               // item +2 (nx)
        float nhv = __shfl_xor(vfin, 6, 64);               // item +3 (nh)

        // ---- (f) publisher epilogue (kc in {0,8}; batch pbb) ----
        if (pub) {
            float hd = hown[par][pbb][u];                  // fp32 carry path
            float r = sigmoidf_(vfin + br);
            float z = sigmoidf_(zv + bz);
            float n = tanhf_(nxv + bnx + r * (nhv + bnh));
            float hnew = (1.f - z) * n + z * hd;
            // publish to LLC first (tag = t+1)
            __hip_atomic_store(hx + (size_t)par * (B * H) + (size_t)(b0 + pbb) * H + row,
                               (((unsigned long long)(unsigned)(t + 1)) << 32) |
                               (unsigned long long)__float_as_uint(hnew),
                               __ATOMIC_RELAXED, __HIP_MEMORY_SCOPE_AGENT);
            // pre-stage own unit's decayed h for t+1 (fp16 for dot2, fp32 carry)
            if (t + 1 < T) {
                float hdn = hnew * __expf(-fmaxf(tdn * hdwo + hdbo, 0.f));
                hdech[par ^ 1][pbb][(row >> 4) * HCS + (row & 15)] = (_Float16)hdn;
                hown[par ^ 1][pbb][u] = hdn;
            }
            out[(size_t)((b0 + pbb) * T + t) * H + row] = hnew;
            if (t == T - 1)
                out[(size_t)B * T * H + (b0 + pbb) * H + row] = hnew;
        }
        // single barrier per step: parity buffering + the collective barrier
        // order all hdec/hown writes before their reads (R4-proven argument).
    }
}

extern "C" void kernel_launch(void* const* d_in, const int* in_sizes, int n_in,
                              void* d_out, int out_size, void* d_ws, size_t ws_size,
                              hipStream_t stream) {
    (void)in_sizes; (void)n_in; (void)out_size; (void)ws_size;
    const float* x    = (const float*)d_in[0];
    const int*   mask = (const int*)d_in[1];
    const float* ts   = (const float*)d_in[2];
    const float* it0  = (const float*)d_in[3];
    const float* w_ih = (const float*)d_in[4];
    const float* w_hh = (const float*)d_in[5];
    const float* b_ih = (const float*)d_in[6];
    const float* b_hh = (const float*)d_in[7];
    const float* idw  = (const float*)d_in[8];
    const float* idb  = (const float*)d_in[9];
    const float* hdw  = (const float*)d_in[10];
    const float* hdb  = (const float*)d_in[11];
    float* out = (float*)d_out;

    // Workspace layout (bytes)
    char* ws = (char*)d_ws;
    _Float16* xh = (_Float16*)(ws);                          // B*T*D f16 = 16777216 B
    float* tdlv  = (float*)(ws + 16777216);                  // 262144 B
    float* mean  = (float*)(ws + 17039360);                  // 32768 B
    unsigned long long* hx = (unsigned long long*)(ws + 17072128); // 2*B*H u64

    // d_out used as scratch before the RNN overwrites it entirely:
    float* ffill  = out;
    float* idelta = out + (size_t)B * T * D;

    // zero tag words each launch (replay safety)
    hipMemsetAsync(hx, 0, (size_t)(2 * B * H) * 8, stream);

    prep_scan<<<dim3(B, 2), 64, 0, stream>>>(x, mask, ts, it0, ffill, idelta, mean, tdlv);
    fill_kernel<<<(B * T) / ROWS, 256, 0, stream>>>(x, mask, ffill, idelta, mean, idw, idb, xh);
    rnn_kernel<<<NG * GK, 1024, 0, stream>>>(xh, tdlv, w_ih, w_hh, b_ih, b_hh, hdw, hdb,
                                             hx, out);
}